// Round 1
// baseline (1076.290 us; speedup 1.0000x reference)
//
#include <hip/hip_runtime.h>
#include <math.h>

// Problem constants
#define HH 128      // hidden
#define DD 2048     // input size
#define BATCH 64
#define TT 256
#define G4 512      // 4*H gates

// ---------------------------------------------------------------------------
// GEMM: C[M,N] = A[M,K] @ B[N,K]^T + bias1[n] + bias2[n]
// A row-major [M,K], B row-major [N,K] (dot over K) -- matches einsum('mk,nk->mn')
// fp32 SIMT, 128x128 tile, TK=16, 256 threads, 8x8 per thread.
// ---------------------------------------------------------------------------
#define BM 128
#define BN 128
#define TK 16
#define GT 256

__global__ __launch_bounds__(GT) void gemm_bias_nt(
    const float* __restrict__ A, const float* __restrict__ Bw,
    const float* __restrict__ b1, const float* __restrict__ b2,
    float* __restrict__ C, int M, int N, int K)
{
    // +4 pad keeps 16B alignment for float4 reads (row length 132 floats)
    __shared__ float As[TK][BM + 4];
    __shared__ float Bs[TK][BN + 4];

    const int tid = threadIdx.x;
    const int tx = tid & 15;        // N direction
    const int ty = tid >> 4;        // M direction
    const int r  = tid >> 2;        // 0..63 load row
    const int kq = (tid & 3) << 2;  // 0,4,8,12 load k-offset

    const float* Ab = A  + (size_t)blockIdx.x * BM * K;
    const float* Bb = Bw + (size_t)blockIdx.y * BN * K;

    float acc[8][8];
#pragma unroll
    for (int i = 0; i < 8; ++i)
#pragma unroll
        for (int j = 0; j < 8; ++j) acc[i][j] = 0.f;

    for (int k0 = 0; k0 < K; k0 += TK) {
        float4 a0  = *(const float4*)(Ab + (size_t)r        * K + k0 + kq);
        float4 a1  = *(const float4*)(Ab + (size_t)(r + 64) * K + k0 + kq);
        float4 b0  = *(const float4*)(Bb + (size_t)r        * K + k0 + kq);
        float4 b1v = *(const float4*)(Bb + (size_t)(r + 64) * K + k0 + kq);
        __syncthreads();   // protect LDS from previous-iter readers
        As[kq+0][r]    = a0.x;  As[kq+1][r]    = a0.y;  As[kq+2][r]    = a0.z;  As[kq+3][r]    = a0.w;
        As[kq+0][r+64] = a1.x;  As[kq+1][r+64] = a1.y;  As[kq+2][r+64] = a1.z;  As[kq+3][r+64] = a1.w;
        Bs[kq+0][r]    = b0.x;  Bs[kq+1][r]    = b0.y;  Bs[kq+2][r]    = b0.z;  Bs[kq+3][r]    = b0.w;
        Bs[kq+0][r+64] = b1v.x; Bs[kq+1][r+64] = b1v.y; Bs[kq+2][r+64] = b1v.z; Bs[kq+3][r+64] = b1v.w;
        __syncthreads();

#pragma unroll
        for (int k = 0; k < TK; ++k) {
            float4 av0 = *(const float4*)&As[k][ty * 4];
            float4 av1 = *(const float4*)&As[k][64 + ty * 4];
            float4 bv0 = *(const float4*)&Bs[k][tx * 4];
            float4 bv1 = *(const float4*)&Bs[k][64 + tx * 4];
            float a[8] = {av0.x, av0.y, av0.z, av0.w, av1.x, av1.y, av1.z, av1.w};
            float b[8] = {bv0.x, bv0.y, bv0.z, bv0.w, bv1.x, bv1.y, bv1.z, bv1.w};
#pragma unroll
            for (int i = 0; i < 8; ++i)
#pragma unroll
                for (int j = 0; j < 8; ++j)
                    acc[i][j] = fmaf(a[i], b[j], acc[i][j]);
        }
    }

    // epilogue with fused dual bias
#pragma unroll
    for (int i = 0; i < 8; ++i) {
        int row = blockIdx.x * BM + ((i < 4) ? (ty * 4 + i) : (64 + ty * 4 + (i - 4)));
        float* crow = C + (size_t)row * N + blockIdx.y * BN;
#pragma unroll
        for (int j = 0; j < 8; ++j) {
            int col = (j < 4) ? (tx * 4 + j) : (64 + tx * 4 + (j - 4));
            int gcol = blockIdx.y * BN + col;
            crow[col] = acc[i][j] + b1[gcol] + b2[gcol];
        }
    }
}

// ---------------------------------------------------------------------------
// LSTM recurrence: one block per batch element (64 blocks, no inter-block sync).
// 512 threads; thread j owns gate row j: Whh[j][0..127] held in 128 VGPRs.
// h (128 fp32) broadcast from LDS each step; gates exchanged via LDS.
// Gate order (PyTorch): [0:128)=i, [128:256)=f, [256:384)=g(tanh), [384:512)=o
// ---------------------------------------------------------------------------
template <bool WRITE_SEQ, bool FINAL_FC>
__global__ __launch_bounds__(512) void lstm_rec(
    const float* __restrict__ xp,    // [64, 256, 512] precomputed input proj (+biases)
    const float* __restrict__ Whh,   // [512, 128]
    float* __restrict__ seq_out,     // [64, 256, 128] (WRITE_SEQ) or null
    const float* __restrict__ Wfc,   // [128] (FINAL_FC) or null
    const float* __restrict__ bfc,   // [1]
    float* __restrict__ out)         // [64] (FINAL_FC)
{
    const int b = blockIdx.x;
    const int j = threadIdx.x;

    __shared__ float h_lds[HH];
    __shared__ float g_lds[G4];

    // Stage my gate's weight row into registers (one-time, ~256KB/block from L2)
    float w[HH];
#pragma unroll
    for (int q = 0; q < 32; ++q) {
        float4 t4 = *(const float4*)(Whh + (size_t)j * HH + q * 4);
        w[4*q+0] = t4.x; w[4*q+1] = t4.y; w[4*q+2] = t4.z; w[4*q+3] = t4.w;
    }

    if (j < HH) h_lds[j] = 0.f;
    float c = 0.f;
    __syncthreads();

    const float* xprow = xp + (size_t)b * TT * G4 + j;
    float xt = xprow[0];   // t=0 prefetched

    for (int t = 0; t < TT; ++t) {
        // prefetch next timestep's input projection early (hides L2/HBM latency)
        int tn = (t + 1 < TT) ? (t + 1) : (TT - 1);
        float xt_next = xprow[(size_t)tn * G4];

        // gate pre-activation: xt + dot(w, h)  -- 4 independent FMA chains
        float s0 = xt, s1 = 0.f, s2 = 0.f, s3 = 0.f;
#pragma unroll
        for (int q = 0; q < 32; ++q) {
            float4 hv = *(const float4*)&h_lds[q * 4];
            s0 = fmaf(w[4*q+0], hv.x, s0);
            s1 = fmaf(w[4*q+1], hv.y, s1);
            s2 = fmaf(w[4*q+2], hv.z, s2);
            s3 = fmaf(w[4*q+3], hv.w, s3);
        }
        float g = (s0 + s1) + (s2 + s3);

        const int gt = j >> 7;   // 0:i 1:f 2:g 3:o
        float act = (gt == 2) ? tanhf(g) : (1.f / (1.f + expf(-g)));
        g_lds[j] = act;
        __syncthreads();         // all gates visible; all h reads of step t done

        if (j < HH) {
            float iv = g_lds[j];
            float fv = g_lds[HH + j];
            float gv = g_lds[2 * HH + j];
            float ov = g_lds[3 * HH + j];
            c = fmaf(fv, c, iv * gv);
            float h = ov * tanhf(c);
            h_lds[j] = h;
            if (WRITE_SEQ)
                seq_out[(size_t)b * TT * HH + (size_t)t * HH + j] = h;
        }
        __syncthreads();         // h update visible before next step's reads
        xt = xt_next;
    }

    if (FINAL_FC) {
        if (j < 64) {
            float p = h_lds[j] * Wfc[j] + h_lds[j + 64] * Wfc[j + 64];
#pragma unroll
            for (int off = 32; off > 0; off >>= 1)
                p += __shfl_down(p, off, 64);
            if (j == 0) out[b] = p + bfc[0];
        }
    }
}

// ---------------------------------------------------------------------------
extern "C" void kernel_launch(void* const* d_in, const int* in_sizes, int n_in,
                              void* d_out, int out_size, void* d_ws, size_t ws_size,
                              hipStream_t stream)
{
    const float* x    = (const float*)d_in[0];
    const float* Wih0 = (const float*)d_in[1];
    const float* Whh0 = (const float*)d_in[2];
    const float* bih0 = (const float*)d_in[3];
    const float* bhh0 = (const float*)d_in[4];
    const float* Wih1 = (const float*)d_in[5];
    const float* Whh1 = (const float*)d_in[6];
    const float* bih1 = (const float*)d_in[7];
    const float* bhh1 = (const float*)d_in[8];
    const float* Wfc  = (const float*)d_in[9];
    const float* bfc  = (const float*)d_in[10];
    float* out = (float*)d_out;

    const int M = BATCH * TT;            // 16384
    float* xp  = (float*)d_ws;           // [16384, 512] fp32 (reused for xp0 then xp1)
    float* seq = xp + (size_t)M * G4;    // [16384, 128] fp32

    // 1) xp0 = x @ Wih0^T + bih0 + bhh0     (34.4 GFLOP, dominant)
    gemm_bias_nt<<<dim3(M / BM, G4 / BN), GT, 0, stream>>>(
        x, Wih0, bih0, bhh0, xp, M, G4, DD);

    // 2) layer-0 recurrence -> seq0
    lstm_rec<true, false><<<BATCH, 512, 0, stream>>>(
        xp, Whh0, seq, nullptr, nullptr, nullptr);

    // 3) xp1 = seq0 @ Wih1^T + bih1 + bhh1  (reuses xp buffer)
    gemm_bias_nt<<<dim3(M / BM, G4 / BN), GT, 0, stream>>>(
        seq, Wih1, bih1, bhh1, xp, M, G4, HH);

    // 4) layer-1 recurrence + fused FC head -> out[64]
    lstm_rec<false, true><<<BATCH, 512, 0, stream>>>(
        xp, Whh1, nullptr, Wfc, bfc, out);
}

// Round 2
// 991.663 us; speedup vs baseline: 1.0853x; 1.0853x over previous
//
#include <hip/hip_runtime.h>
#include <math.h>

#define HH 128      // hidden
#define DD 2048     // input size
#define BATCH 64
#define TT 256
#define G4 512      // 4*H

typedef __attribute__((ext_vector_type(8))) short bf16x8;   // 8 bf16 = 4 VGPRs
typedef __attribute__((ext_vector_type(4))) float f32x4;
typedef _Float16 h2 __attribute__((ext_vector_type(2)));

// ---- helpers ---------------------------------------------------------------
static __device__ __forceinline__ unsigned short f2bf_rne(float f) {
    union { float f; unsigned u; } v; v.f = f;
    unsigned r = v.u + 0x7fff + ((v.u >> 16) & 1);   // round-nearest-even
    return (unsigned short)(r >> 16);
}
static __device__ __forceinline__ float bf2f(unsigned short b) {
    union { unsigned u; float f; } v; v.u = ((unsigned)b) << 16;
    return v.f;
}
static __device__ __forceinline__ float fdot2f(h2 a, h2 b, float c) {
#if __has_builtin(__builtin_amdgcn_fdot2)
    return __builtin_amdgcn_fdot2(a, b, c, false);
#else
    return fmaf((float)a[0], (float)b[0], fmaf((float)a[1], (float)b[1], c));
#endif
}
static __device__ __forceinline__ float fexp2(float x) {
#if __has_builtin(__builtin_amdgcn_exp2f)
    return __builtin_amdgcn_exp2f(x);
#else
    return exp2f(x);
#endif
}
static __device__ __forceinline__ float frcp(float x) {
#if __has_builtin(__builtin_amdgcn_rcpf)
    return __builtin_amdgcn_rcpf(x);
#else
    return 1.f / x;
#endif
}
static __device__ __forceinline__ float sigmoid_f(float x) {
    return frcp(1.f + fexp2(-1.44269504f * x));
}
static __device__ __forceinline__ float tanh_f(float x) {
    float xx = fminf(fmaxf(x, -15.f), 15.f);
    float e = fexp2(2.88539008f * xx);               // exp(2x)
    return 1.f - 2.f * frcp(e + 1.f);
}

// ---------------------------------------------------------------------------
// Split-bf16 GEMM: C[M,N] = A[M,K] @ B[N,K]^T + b1[n] + b2[n], fp32 in/out.
// a = a_hi + a_lo (bf16 each); C ~ a_hi@b_hi + a_hi@b_lo + a_lo@b_hi (fp32 acc)
// 128x128 tile, BK=32, 256 threads = 4 waves (2x2), wave tile 64x64 via
// 4x4 frags of v_mfma_f32_16x16x32_bf16.
// ---------------------------------------------------------------------------
#define PK 40   // LDS row stride in halves (80 B): 16B-aligned rows, ~2-way banks

__global__ __launch_bounds__(256) void gemm_split_bf16(
    const float* __restrict__ A, const float* __restrict__ Bw,
    const float* __restrict__ b1, const float* __restrict__ b2,
    float* __restrict__ C, int M, int N, int K)
{
    __shared__ unsigned short Ah[128 * PK], Al[128 * PK];
    __shared__ unsigned short Bh[128 * PK], Bl[128 * PK];

    const int tid = threadIdx.x;
    const int l = tid & 63;
    const int w = tid >> 6;
    const int wr = w >> 1, wc = w & 1;       // 2x2 wave grid
    const int bm = blockIdx.y, bn = blockIdx.x;

    f32x4 acc[4][4];
#pragma unroll
    for (int m = 0; m < 4; ++m)
#pragma unroll
        for (int n = 0; n < 4; ++n) acc[m][n] = f32x4{0.f, 0.f, 0.f, 0.f};

    const float* Ab = A  + (size_t)(bm * 128) * K;
    const float* Bb = Bw + (size_t)(bn * 128) * K;

    for (int k0 = 0; k0 < K; k0 += 32) {
        __syncthreads();   // protect LDS from previous iteration's readers
        // ---- stage + on-the-fly hi/lo bf16 split --------------------------
#pragma unroll
        for (int q = 0; q < 4; ++q) {
            int fid = tid + 256 * q;          // 0..1023 float4-slots of 128x32 tile
            int r = fid >> 3;                 // 0..127
            int kk = (fid & 7) << 2;          // 0..28
            float4 av = *(const float4*)(Ab + (size_t)r * K + k0 + kk);
            float4 bv = *(const float4*)(Bb + (size_t)r * K + k0 + kk);
            float a4[4] = {av.x, av.y, av.z, av.w};
            float b4[4] = {bv.x, bv.y, bv.z, bv.w};
            ushort4 ahv, alv, bhv, blv;
            unsigned short t;
            t = f2bf_rne(a4[0]); ahv.x = t; alv.x = f2bf_rne(a4[0] - bf2f(t));
            t = f2bf_rne(a4[1]); ahv.y = t; alv.y = f2bf_rne(a4[1] - bf2f(t));
            t = f2bf_rne(a4[2]); ahv.z = t; alv.z = f2bf_rne(a4[2] - bf2f(t));
            t = f2bf_rne(a4[3]); ahv.w = t; alv.w = f2bf_rne(a4[3] - bf2f(t));
            t = f2bf_rne(b4[0]); bhv.x = t; blv.x = f2bf_rne(b4[0] - bf2f(t));
            t = f2bf_rne(b4[1]); bhv.y = t; blv.y = f2bf_rne(b4[1] - bf2f(t));
            t = f2bf_rne(b4[2]); bhv.z = t; blv.z = f2bf_rne(b4[2] - bf2f(t));
            t = f2bf_rne(b4[3]); bhv.w = t; blv.w = f2bf_rne(b4[3] - bf2f(t));
            int off = r * PK + kk;
            *(ushort4*)&Ah[off] = ahv;
            *(ushort4*)&Al[off] = alv;
            *(ushort4*)&Bh[off] = bhv;
            *(ushort4*)&Bl[off] = blv;
        }
        __syncthreads();

        // ---- fragments + MFMA --------------------------------------------
        bf16x8 aH[4], aL[4], bH[4], bL[4];
#pragma unroll
        for (int m = 0; m < 4; ++m) {
            int row = wr * 64 + m * 16 + (l & 15);
            int off = row * PK + 8 * (l >> 4);
            aH[m] = *(const bf16x8*)&Ah[off];
            aL[m] = *(const bf16x8*)&Al[off];
        }
#pragma unroll
        for (int n = 0; n < 4; ++n) {
            int row = wc * 64 + n * 16 + (l & 15);
            int off = row * PK + 8 * (l >> 4);
            bH[n] = *(const bf16x8*)&Bh[off];
            bL[n] = *(const bf16x8*)&Bl[off];
        }
#pragma unroll
        for (int m = 0; m < 4; ++m)
#pragma unroll
            for (int n = 0; n < 4; ++n) {
                acc[m][n] = __builtin_amdgcn_mfma_f32_16x16x32_bf16(aH[m], bH[n], acc[m][n], 0, 0, 0);
                acc[m][n] = __builtin_amdgcn_mfma_f32_16x16x32_bf16(aH[m], bL[n], acc[m][n], 0, 0, 0);
                acc[m][n] = __builtin_amdgcn_mfma_f32_16x16x32_bf16(aL[m], bH[n], acc[m][n], 0, 0, 0);
            }
    }

    // ---- epilogue: C = acc + b1 + b2  (C/D layout: col=l&15, row=(l>>4)*4+i)
#pragma unroll
    for (int n = 0; n < 4; ++n) {
        int cg = bn * 128 + wc * 64 + n * 16 + (l & 15);
        float bias = b1[cg] + b2[cg];
#pragma unroll
        for (int m = 0; m < 4; ++m) {
            int r0 = bm * 128 + wr * 64 + m * 16 + ((l >> 4) << 2);
            f32x4 v = acc[m][n];
#pragma unroll
            for (int i = 0; i < 4; ++i)
                C[(size_t)(r0 + i) * N + cg] = v[i] + bias;
        }
    }
}

// ---------------------------------------------------------------------------
// LSTM recurrence, fp16-dot2 version.
// One block per batch (64 blocks), 128 threads (2 waves). Thread j owns the
// FOUR gate rows (i,f,g,o) of hidden unit j: 4x128 fp16 weights = 256 VGPRs
// (packed half2). h kept in LDS as fp16, double-buffered -> ONE barrier/step.
// Per step: 16 b128 LDS broadcasts + 256 v_dot2_f32_f16 per thread.
// ---------------------------------------------------------------------------
template <bool WRITE_SEQ, bool FINAL_FC>
__global__ __launch_bounds__(128, 1) void lstm_rec_f16(
    const float* __restrict__ xp,    // [64,256,512] input proj (+both biases)
    const float* __restrict__ Whh,   // [512,128] fp32
    float* __restrict__ seq_out,     // [64,256,128] (WRITE_SEQ)
    const float* __restrict__ Wfc,   // [128] (FINAL_FC)
    const float* __restrict__ bfc,   // [1]
    float* __restrict__ out)         // [64]
{
    const int b = blockIdx.x;
    const int j = threadIdx.x;

    __shared__ alignas(16) _Float16 hbuf[2][HH];
    __shared__ float red[2];

    // preload 4 gate rows as packed half2 (rows j, 128+j, 256+j, 384+j)
    h2 wreg[4][64];
#pragma unroll
    for (int g = 0; g < 4; ++g) {
        const float4* wrow = (const float4*)(Whh + (size_t)(g * HH + j) * HH);
#pragma unroll
        for (int q = 0; q < 32; ++q) {
            float4 t = wrow[q];
            wreg[g][2 * q]     = h2{(_Float16)t.x, (_Float16)t.y};
            wreg[g][2 * q + 1] = h2{(_Float16)t.z, (_Float16)t.w};
        }
    }

    hbuf[0][j] = (_Float16)0.f;
    float c = 0.f, hlast = 0.f;

    const float* xb = xp + (size_t)b * TT * G4;
    float xi = xb[j], xf = xb[HH + j], xg = xb[2 * HH + j], xo = xb[3 * HH + j];
    __syncthreads();

    int cur = 0;
    for (int t = 0; t < TT; ++t) {
        // prefetch next timestep's xp (consumed next iteration)
        const float* xn = xb + (size_t)(t + 1 < TT ? t + 1 : t) * G4;
        float ni = xn[j], nf = xn[HH + j], ng = xn[2 * HH + j], no = xn[3 * HH + j];

        float ai = xi, af = xf, ag = xg, ao = xo;
        const uint4* hp = (const uint4*)&hbuf[cur][0];
#pragma unroll
        for (int q = 0; q < 16; ++q) {
            uint4 hv = hp[q];                        // 8 halves, wave-uniform bcast
            union { unsigned u; h2 h; } c0, c1, c2, c3;
            c0.u = hv.x; c1.u = hv.y; c2.u = hv.z; c3.u = hv.w;
            ai = fdot2f(wreg[0][4*q+0], c0.h, ai); ai = fdot2f(wreg[0][4*q+1], c1.h, ai);
            ai = fdot2f(wreg[0][4*q+2], c2.h, ai); ai = fdot2f(wreg[0][4*q+3], c3.h, ai);
            af = fdot2f(wreg[1][4*q+0], c0.h, af); af = fdot2f(wreg[1][4*q+1], c1.h, af);
            af = fdot2f(wreg[1][4*q+2], c2.h, af); af = fdot2f(wreg[1][4*q+3], c3.h, af);
            ag = fdot2f(wreg[2][4*q+0], c0.h, ag); ag = fdot2f(wreg[2][4*q+1], c1.h, ag);
            ag = fdot2f(wreg[2][4*q+2], c2.h, ag); ag = fdot2f(wreg[2][4*q+3], c3.h, ag);
            ao = fdot2f(wreg[3][4*q+0], c0.h, ao); ao = fdot2f(wreg[3][4*q+1], c1.h, ao);
            ao = fdot2f(wreg[3][4*q+2], c2.h, ao); ao = fdot2f(wreg[3][4*q+3], c3.h, ao);
        }

        float iv = sigmoid_f(ai);
        float fv = sigmoid_f(af);
        float ov = sigmoid_f(ao);
        float gv = tanh_f(ag);
        c = fmaf(fv, c, iv * gv);
        float h = ov * tanh_f(c);

        hbuf[cur ^ 1][j] = (_Float16)h;            // write OTHER buffer -> no WAR
        if (WRITE_SEQ)
            seq_out[((size_t)b * TT + t) * HH + j] = h;
        hlast = h;
        __syncthreads();                           // single barrier per step
        cur ^= 1;
        xi = ni; xf = nf; xg = ng; xo = no;
    }

    if (FINAL_FC) {
        float p = hlast * Wfc[j];
#pragma unroll
        for (int off = 32; off > 0; off >>= 1) p += __shfl_down(p, off, 64);
        if ((j & 63) == 0) red[j >> 6] = p;
        __syncthreads();
        if (j == 0) out[b] = red[0] + red[1] + bfc[0];
    }
}

// ---------------------------------------------------------------------------
extern "C" void kernel_launch(void* const* d_in, const int* in_sizes, int n_in,
                              void* d_out, int out_size, void* d_ws, size_t ws_size,
                              hipStream_t stream)
{
    const float* x    = (const float*)d_in[0];
    const float* Wih0 = (const float*)d_in[1];
    const float* Whh0 = (const float*)d_in[2];
    const float* bih0 = (const float*)d_in[3];
    const float* bhh0 = (const float*)d_in[4];
    const float* Wih1 = (const float*)d_in[5];
    const float* Whh1 = (const float*)d_in[6];
    const float* bih1 = (const float*)d_in[7];
    const float* bhh1 = (const float*)d_in[8];
    const float* Wfc  = (const float*)d_in[9];
    const float* bfc  = (const float*)d_in[10];
    float* out = (float*)d_out;

    const int M = BATCH * TT;              // 16384
    float* xp  = (float*)d_ws;             // [16384,512]
    float* seq = xp + (size_t)M * G4;      // [16384,128]

    // 1) xp0 = x @ Wih0^T + bih0 + bhh0   (K=2048; grid x=bn fastest for A L2 reuse)
    gemm_split_bf16<<<dim3(G4 / 128, M / 128), 256, 0, stream>>>(
        x, Wih0, bih0, bhh0, xp, M, G4, DD);

    // 2) layer-0 recurrence -> seq
    lstm_rec_f16<true, false><<<BATCH, HH, 0, stream>>>(
        xp, Whh0, seq, nullptr, nullptr, nullptr);

    // 3) xp1 = seq @ Wih1^T + bih1 + bhh1 (K=128)
    gemm_split_bf16<<<dim3(G4 / 128, M / 128), 256, 0, stream>>>(
        seq, Wih1, bih1, bhh1, xp, M, G4, HH);

    // 4) layer-1 recurrence + fused FC head
    lstm_rec_f16<false, true><<<BATCH, HH, 0, stream>>>(
        xp, Whh1, nullptr, Wfc, bfc, out);
}